// Round 10
// baseline (419.382 us; speedup 1.0000x reference)
//
#include <hip/hip_runtime.h>

#define HH 384
#define WW 384
#define HWSZ (HH * WW)          // 147456
#define NPLANES 128             // 2 batch * 64 chan
#define CHN 64
#define VSTRIPS 4
#define STRIP_H 96              // HH / VSTRIPS
#define RING 48                 // LDS ring rows
#define RSTRIDE 416             // 16 left pad + 384 + 15 right pad (+1 align)
#define NACC 11
#define NSUPER 22               // 16 compute groups + 6 lag
#define QP (HWSZ / 4)           // 36864 float4 per plane
#define NINQ (NPLANES * QP)     // 4,718,592 input quads
#define OB 2048
#define OT 256
#define OITER (NINQ / (OB * OT))   // 9, exact
#define NREP 5                  // measurement: 5 identical passes in one dispatch

typedef float f4 __attribute__((ext_vector_type(4)));

// Ring row layout: [0..15]=0 (P[-k]), [16+c]=P[c], [400..414]=P[383].
__global__ __launch_bounds__(384, 3) void stats_fused(const float* __restrict__ x,
                                                      float* __restrict__ partials) {
    __shared__ float ring[RING][RSTRIDE];   // 79,872 B
    __shared__ float redbuf[6 * NACC];

    const int t = threadIdx.x;              // column 0..383
    const int lane = t & 63;
    const int wv = t >> 6;
    const int bid = blockIdx.x;
    const int p = bid >> 2;                 // plane
    const int s = bid & 3;                  // strip
    const int y0 = s * STRIP_H;
    const float* __restrict__ xp = x + (size_t)p * HWSZ;

    const int W2S[3] = {3, 7, 15};          // l=0 -> w7, l=1 -> w15, l=2 -> w31
    float invcx[3];
#pragma unroll
    for (int i = 0; i < 3; ++i) {
        int w2 = W2S[i];
        int hi = t + w2; if (hi > WW - 1) hi = WW - 1;
        int lo = t - w2; if (lo < 0) lo = 0;
        invcx[i] = 1.0f / (float)(hi - lo + 1);
    }

    // zero the left pads once (staging never touches cols < 16)
    for (int idx = t; idx < RING * 16; idx += 384)
        ring[idx >> 4][idx & 15] = 0.f;

    // MEASUREMENT: repeat the identical pass NREP times in ONE dispatch so the
    // stats kernel exceeds the harness fills (~170us) and surfaces in the
    // rocprof top-5 with its real counters. volatile store defeats DSE.
    volatile float* vpart = partials;
#pragma unroll 1
    for (int rep = 0; rep < NREP; ++rep) {
        float bsum[3] = {0.f, 0.f, 0.f};
        float Aa[3] = {0.f, 0.f, 0.f};
        float Bb[3] = {0.f, 0.f, 0.f};
        float Cc[3] = {0.f, 0.f, 0.f};
        float T1 = 0.f, T2 = 0.f;

        // register prefetch of group-0 row (wave-private)
        float2 A0 = {0.f, 0.f}, A1 = {0.f, 0.f}, A2 = {0.f, 0.f};
        {
            int r = y0 - 16 + wv;
            if ((unsigned)r < (unsigned)HH) {
                const float* src = xp + (size_t)r * WW + lane * 6;
                A0 = *(const float2*)(src);
                A1 = *(const float2*)(src + 2);
                A2 = *(const float2*)(src + 4);
            }
        }

        int by = 16;                        // ring slot of current compute row y0
        for (int k = 0; k < NSUPER; ++k) {
            const int u = 6 * k + wv;       // slot sequence 0..131
            const int r = y0 - 16 + u;      // absolute row
            int slot = u;
            if (slot >= 96) slot -= 96; else if (slot >= 48) slot -= 48;

            if (u <= 126) {                 // r <= y0+110: this slot will be read
                float* dst = ring[slot];
                if ((unsigned)r < (unsigned)HH) {
                    float s0 = A0.x, s1 = s0 + A0.y, s2 = s1 + A1.x;
                    float s3 = s2 + A1.y, s4 = s3 + A2.x, s5 = s4 + A2.y;
                    float tot = s5, e = tot;
#pragma unroll
                    for (int d = 1; d < 64; d <<= 1) {
                        float uu = __shfl_up(e, d, 64);
                        if (lane >= d) e += uu;
                    }
                    e -= tot;               // exclusive offset of lane totals
                    float p383 = __shfl(s5 + e, 63, 64);
                    float* dp = dst + 16 + lane * 6;
                    *(float2*)(dp)     = make_float2(s0 + e, s1 + e);
                    *(float2*)(dp + 2) = make_float2(s2 + e, s3 + e);
                    *(float2*)(dp + 4) = make_float2(s4 + e, s5 + e);
                    if (lane < 15) dst[400 + lane] = p383;   // right pad = P[383]
                } else {
                    float* dp = dst + 16 + lane * 6;
                    *(float2*)(dp)     = make_float2(0.f, 0.f);
                    *(float2*)(dp + 2) = make_float2(0.f, 0.f);
                    *(float2*)(dp + 4) = make_float2(0.f, 0.f);
                    if (lane < 15) dst[400 + lane] = 0.f;
                }
            }
            if (k < NSUPER - 1) {           // prefetch next group's row
                int rn = r + 6;
                if (u + 6 <= 126 && (unsigned)rn < (unsigned)HH) {
                    const float* src = xp + (size_t)rn * WW + lane * 6;
                    A0 = *(const float2*)(src);
                    A1 = *(const float2*)(src + 2);
                    A2 = *(const float2*)(src + 4);
                }
            }
            __syncthreads();                // one barrier per superstep

            int j = k - 6;
            if (j >= 0) {
                if (j == 0) {               // prime vertical box sums at y = y0
#pragma unroll
                    for (int i = 0; i < 3; ++i) {
                        int w2 = W2S[i];
                        float sum = 0.f;
                        for (int rr = -w2; rr <= w2; ++rr) {
                            const float* pr = &ring[16 + rr][t];
                            sum += pr[16 + w2] - pr[15 - w2];
                        }
                        bsum[i] = sum;
                    }
                }
#pragma unroll
                for (int dy = 0; dy < 6; ++dy) {
                    int y = y0 + 6 * j + dy;
                    if (j > 0 || dy > 0) {
                        int e0 = by + 3;  if (e0 >= RING) e0 -= RING;
                        int e1 = by + 7;  if (e1 >= RING) e1 -= RING;
                        int e2 = by + 15; if (e2 >= RING) e2 -= RING;
                        int l0 = by - 4;  if (l0 < 0) l0 += RING;
                        int l1 = by - 8;  if (l1 < 0) l1 += RING;
                        int l2 = by - 16; if (l2 < 0) l2 += RING;
                        const float* pe0 = &ring[e0][t];
                        const float* pe1 = &ring[e1][t];
                        const float* pe2 = &ring[e2][t];
                        const float* pl0 = &ring[l0][t];
                        const float* pl1 = &ring[l1][t];
                        const float* pl2 = &ring[l2][t];
                        bsum[0] += (pe0[19] - pe0[12]) - (pl0[19] - pl0[12]);
                        bsum[1] += (pe1[23] - pe1[8])  - (pl1[23] - pl1[8]);
                        bsum[2] += (pe2[31] - pe2[0])  - (pl2[31] - pl2[0]);
                    }
                    const float* pr = &ring[by][t];
                    float xv = pr[16] - pr[15];         // recover x[y][t]
                    T1 += xv;
                    T2 = fmaf(xv, xv, T2);
#pragma unroll
                    for (int i = 0; i < 3; ++i) {
                        int w2 = W2S[i];
                        int chi = y + w2; if (chi > HH - 1) chi = HH - 1;
                        int clo = y - w2; if (clo < 0) clo = 0;
                        float invcy = __builtin_amdgcn_rcpf((float)(chi - clo + 1));
                        float m = bsum[i] * (invcy * invcx[i]);
                        Aa[i] += m;
                        Bb[i] = fmaf(xv, m, Bb[i]);
                        Cc[i] = fmaf(m, m, Cc[i]);
                    }
                    ++by; if (by >= RING) by = 0;
                }
            }
        }

        // deterministic block reduction of the 11 accumulators
        float acc[NACC] = {Aa[0], Bb[0], Cc[0], Aa[1], Bb[1], Cc[1],
                           Aa[2], Bb[2], Cc[2], T1, T2};
#pragma unroll
        for (int q = 0; q < NACC; ++q) {
#pragma unroll
            for (int d = 32; d >= 1; d >>= 1) acc[q] += __shfl_xor(acc[q], d, 64);
        }
        if (lane == 0) {
#pragma unroll
            for (int q = 0; q < NACC; ++q) redbuf[wv * NACC + q] = acc[q];
        }
        __syncthreads();
        if (t < NACC) {
            float ssum = 0.f;
#pragma unroll
            for (int w = 0; w < 6; ++w) ssum += redbuf[w * NACC + t];
            vpart[bid * NACC + t] = ssum;   // volatile: all reps' stores kept
        }
        __syncthreads();                    // protect ring before next rep stages
    }
}

// ---- per-(plane, l) std -> reciprocal scale; scales[op], op=(b*4+l)*64+c ----
__global__ __launch_bounds__(128) void scales_kernel(const float* __restrict__ partials,
                                                     const float* __restrict__ tiny,
                                                     float* __restrict__ scales) {
    int p = threadIdx.x;
    if (p >= NPLANES) return;
    int b = p >> 6, c = p & 63;
    float acc[NACC];
#pragma unroll
    for (int q = 0; q < NACC; ++q) acc[q] = 0.f;
    for (int s = 0; s < VSTRIPS; ++s) {
#pragma unroll
        for (int q = 0; q < NACC; ++q)
            acc[q] += partials[(p * VSTRIPS + s) * NACC + q];
    }
    const float Nf = (float)HWSZ;
    const float invNm1 = 1.0f / (float)(HWSZ - 1);
    float T1 = acc[9], T2 = acc[10];
    float thr = tiny[c] + 1e-6f;
#pragma unroll
    for (int l = 0; l < 4; ++l) {
        float S, Q;
        if (l < 3) {
            S = T1 - acc[l * 3 + 0];
            Q = T2 - 2.f * acc[l * 3 + 1] + acc[l * 3 + 2];
        } else {
            S = T1;     // var(x - mean(x)) == var(x)
            Q = T2;
        }
        float var = (Q - S * S / Nf) * invNm1;
        float sd = sqrtf(fmaxf(var, 0.f));
        sd = fmaxf(sd, thr);
        scales[(b * 4 + l) * CHN + c] = 1.0f / sd;
    }
}

// ---- out: persistent grid-stride, 1 coalesced read -> 4 nt-store streams (R8 best) ----
__global__ __launch_bounds__(256) void out_kernel(const float* __restrict__ x,
                                                  const float* __restrict__ scales,
                                                  float* __restrict__ out) {
    __shared__ float ls[512];
    ls[threadIdx.x] = scales[threadIdx.x];
    ls[threadIdx.x + 256] = scales[threadIdx.x + 256];
    __syncthreads();

    const unsigned stride = OB * OT;                 // 524288
    const unsigned base = blockIdx.x * OT + threadIdx.x;
    const f4* __restrict__ xq = (const f4*)x;
    f4* __restrict__ oq = (f4*)out;

    f4 v = xq[base];
#pragma unroll
    for (int it = 0; it < OITER; ++it) {
        unsigned i = base + it * stride;
        f4 cur = v;
        if (it + 1 < OITER) v = xq[i + stride];      // prefetch next iter
        unsigned plane = i / QP;                     // wave-uniform (QP%64==0)
        unsigned q = i - plane * QP;
        unsigned b = plane >> 6, c = plane & 63;
        size_t o0 = (size_t)(b * 256 + c) * QP + q;  // l=0 output quad index
#pragma unroll
        for (int l = 0; l < 4; ++l) {
            f4 o = cur * ls[b * 256 + l * 64 + c];
            __builtin_nontemporal_store(o, oq + o0 + (size_t)l * 64 * QP);
        }
    }
}

extern "C" void kernel_launch(void* const* d_in, const int* in_sizes, int n_in,
                              void* d_out, int out_size, void* d_ws, size_t ws_size,
                              hipStream_t stream) {
    const float* x = (const float*)d_in[0];
    const float* tiny = (const float*)d_in[1];
    float* out = (float*)d_out;

    float* partials = (float*)d_ws;                              // 512*11 floats
    float* scales = partials + NPLANES * VSTRIPS * NACC;         // 512 floats

    stats_fused<<<NPLANES * VSTRIPS, 384, 0, stream>>>(x, partials);
    scales_kernel<<<1, 128, 0, stream>>>(partials, tiny, scales);
    out_kernel<<<OB, OT, 0, stream>>>(x, scales, out);
}

// Round 11
// 146.626 us; speedup vs baseline: 2.8602x; 2.8602x over previous
//
#include <hip/hip_runtime.h>

#define HH 384
#define WW 384
#define HWSZ (HH * WW)          // 147456
#define NPLANES 128             // 2 batch * 64 chan
#define CHN 64
#define VSTRIPS 4
#define STRIP_H 96              // HH / VSTRIPS
#define RING 48                 // LDS ring rows (exact span for 12-row lag-3 schedule)
#define RSTRIDE 416             // 16 left pad + 384 + 15 right pad (+1 align)
#define NACC 11
#define NSUP 11                 // 11 stage groups of 12 rows; compute lags 3 groups
#define QP (HWSZ / 4)           // 36864 float4 per plane
#define NINQ (NPLANES * QP)     // 4,718,592 input quads
#define OB 2048
#define OT 256
#define OITER (NINQ / (OB * OT))   // 9, exact

typedef float f4 __attribute__((ext_vector_type(4)));

// Ring row layout: [0..15]=0 (P[-k]), [16+c]=P[c], [400..414]=P[383].
__global__ __launch_bounds__(384, 3) void stats_fused(const float* __restrict__ x,
                                                      float* __restrict__ partials) {
    __shared__ float ring[RING][RSTRIDE];   // 79,872 B
    __shared__ float redbuf[6 * NACC];

    const int t = threadIdx.x;              // column 0..383
    const int lane = t & 63;
    const int wv = t >> 6;
    const int bid = blockIdx.x;
    const int p = bid >> 2;                 // plane
    const int s = bid & 3;                  // strip
    const int y0 = s * STRIP_H;
    const float* __restrict__ xp = x + (size_t)p * HWSZ;

    const int W2S[3] = {3, 7, 15};          // l=0 -> w7, l=1 -> w15, l=2 -> w31
    float invcx[3], fmul[3];
#pragma unroll
    for (int i = 0; i < 3; ++i) {
        int w2 = W2S[i];
        int hi = t + w2; if (hi > WW - 1) hi = WW - 1;
        int lo = t - w2; if (lo < 0) lo = 0;
        invcx[i] = 1.0f / (float)(hi - lo + 1);
        fmul[i] = invcx[i] * (1.0f / (float)(2 * w2 + 1));   // interior invcy folded in
    }

    // zero the left pads once (staging never touches cols < 16)
    for (int idx = t; idx < RING * 16; idx += 384)
        ring[idx >> 4][idx & 15] = 0.f;

    float bs0 = 0.f, bs1 = 0.f, bs2 = 0.f;  // vertical running box sums
    float Aa[3] = {0.f, 0.f, 0.f};
    float Bb[3] = {0.f, 0.f, 0.f};
    float Cc[3] = {0.f, 0.f, 0.f};
    float T1 = 0.f, T2 = 0.f;

    // prefetch stage-group 0: wave handles rows u=wv and u=wv+6
    float2 A0 = {0,0}, A1 = {0,0}, A2 = {0,0};
    float2 B0 = {0,0}, B1 = {0,0}, B2 = {0,0};
    {
        int r1 = y0 - 16 + wv;
        if ((unsigned)r1 < (unsigned)HH) {
            const float* src = xp + (size_t)r1 * WW + lane * 6;
            A0 = *(const float2*)(src); A1 = *(const float2*)(src + 2); A2 = *(const float2*)(src + 4);
        }
        int r2 = r1 + 6;
        if ((unsigned)r2 < (unsigned)HH) {
            const float* src = xp + (size_t)r2 * WW + lane * 6;
            B0 = *(const float2*)(src); B1 = *(const float2*)(src + 2); B2 = *(const float2*)(src + 4);
        }
    }

    int by = 16;                            // ring slot of current compute row
    for (int k = 0; k < NSUP; ++k) {
        const int u1 = 12 * k + wv;         // this wave's two staged rows
        const int u2 = u1 + 6;
        {
            // two independent scans, shfl chains interleaved
            float a0 = A0.x, a1 = a0 + A0.y, a2 = a1 + A1.x;
            float a3 = a2 + A1.y, a4 = a3 + A2.x, a5 = a4 + A2.y;
            float b0 = B0.x, b1 = b0 + B0.y, b2 = b1 + B1.x;
            float b3 = b2 + B1.y, b4 = b3 + B2.x, b5 = b4 + B2.y;
            float ea = a5, eb = b5;
#pragma unroll
            for (int d = 1; d < 64; d <<= 1) {
                float ua = __shfl_up(ea, d, 64);
                float ub = __shfl_up(eb, d, 64);
                if (lane >= d) { ea += ua; eb += ub; }
            }
            ea -= a5; eb -= b5;             // exclusive offsets
            float pa383 = __shfl(a5 + ea, 63, 64);
            float pb383 = __shfl(b5 + eb, 63, 64);
            if (u1 <= 126) {
                int sl = u1; if (sl >= 96) sl -= 96; else if (sl >= 48) sl -= 48;
                float* dst = ring[sl]; float* dp = dst + 16 + lane * 6;
                *(float2*)(dp)     = make_float2(a0 + ea, a1 + ea);
                *(float2*)(dp + 2) = make_float2(a2 + ea, a3 + ea);
                *(float2*)(dp + 4) = make_float2(a4 + ea, a5 + ea);
                if (lane < 15) dst[400 + lane] = pa383;
            }
            if (u2 <= 126) {
                int sl = u2; if (sl >= 96) sl -= 96; else if (sl >= 48) sl -= 48;
                float* dst = ring[sl]; float* dp = dst + 16 + lane * 6;
                *(float2*)(dp)     = make_float2(b0 + eb, b1 + eb);
                *(float2*)(dp + 2) = make_float2(b2 + eb, b3 + eb);
                *(float2*)(dp + 4) = make_float2(b4 + eb, b5 + eb);
                if (lane < 15) dst[400 + lane] = pb383;
            }
        }
        if (k < NSUP - 1) {                 // prefetch next stage group
            A0 = A1 = A2 = B0 = B1 = B2 = make_float2(0.f, 0.f);
            int r1 = y0 - 16 + u1 + 12;
            if (u1 + 12 <= 126 && (unsigned)r1 < (unsigned)HH) {
                const float* src = xp + (size_t)r1 * WW + lane * 6;
                A0 = *(const float2*)(src); A1 = *(const float2*)(src + 2); A2 = *(const float2*)(src + 4);
            }
            int r2 = r1 + 6;
            if (u2 + 12 <= 126 && (unsigned)r2 < (unsigned)HH) {
                const float* src = xp + (size_t)r2 * WW + lane * 6;
                B0 = *(const float2*)(src); B1 = *(const float2*)(src + 2); B2 = *(const float2*)(src + 4);
            }
        }
        __syncthreads();                    // one barrier per superstep (11 total)

        int j = k - 3;
        if (j >= 0) {
            const int Y = y0 + 12 * j;
            if (j == 0) {                   // prime box sums at y = y0 (slots 1..31)
#pragma unroll
                for (int i = 0; i < 3; ++i) {
                    int w2 = W2S[i];
                    float sum = 0.f;
                    for (int rr = -w2; rr <= w2; ++rr) {
                        const float* pr = &ring[16 + rr][t];
                        sum += pr[16 + w2] - pr[15 - w2];
                    }
                    if (i == 0) bs0 = sum; else if (i == 1) bs1 = sum; else bs2 = sum;
                }
            }
            const bool fast = (Y >= 15) && (Y + 11 <= 368);   // wave-uniform
            if (fast) {
#pragma unroll
                for (int dy = 0; dy < 12; ++dy) {
                    const float* pr = &ring[by][t];
                    float xv = pr[16] - pr[15];
                    T1 += xv;
                    T2 = fmaf(xv, xv, T2);
                    float m0 = bs0 * fmul[0], m1 = bs1 * fmul[1], m2 = bs2 * fmul[2];
                    Aa[0] += m0; Bb[0] = fmaf(xv, m0, Bb[0]); Cc[0] = fmaf(m0, m0, Cc[0]);
                    Aa[1] += m1; Bb[1] = fmaf(xv, m1, Bb[1]); Cc[1] = fmaf(m1, m1, Cc[1]);
                    Aa[2] += m2; Bb[2] = fmaf(xv, m2, Bb[2]); Cc[2] = fmaf(m2, m2, Cc[2]);
                    // advance bsum to y+1: enter y+1+w2, leave y-w2
                    int e0 = by + 4;  if (e0 >= RING) e0 -= RING;
                    int e1 = by + 8;  if (e1 >= RING) e1 -= RING;
                    int e2 = by + 16; if (e2 >= RING) e2 -= RING;
                    int l0 = by - 3;  if (l0 < 0) l0 += RING;
                    int l1 = by - 7;  if (l1 < 0) l1 += RING;
                    int l2 = by - 15; if (l2 < 0) l2 += RING;
                    const float* pe0 = &ring[e0][t]; const float* pl0 = &ring[l0][t];
                    const float* pe1 = &ring[e1][t]; const float* pl1 = &ring[l1][t];
                    const float* pe2 = &ring[e2][t]; const float* pl2 = &ring[l2][t];
                    bs0 += (pe0[19] - pe0[12]) - (pl0[19] - pl0[12]);
                    bs1 += (pe1[23] - pe1[8])  - (pl1[23] - pl1[8]);
                    bs2 += (pe2[31] - pe2[0])  - (pl2[31] - pl2[0]);
                    ++by; if (by >= RING) by = 0;
                }
            } else {
#pragma unroll
                for (int dy = 0; dy < 12; ++dy) {
                    int y = Y + dy;
                    const float* pr = &ring[by][t];
                    float xv = pr[16] - pr[15];
                    T1 += xv;
                    T2 = fmaf(xv, xv, T2);
#pragma unroll
                    for (int i = 0; i < 3; ++i) {
                        int w2 = W2S[i];
                        int chi = y + w2; if (chi > HH - 1) chi = HH - 1;
                        int clo = y - w2; if (clo < 0) clo = 0;
                        float invcy = __builtin_amdgcn_rcpf((float)(chi - clo + 1));
                        float bsv = (i == 0) ? bs0 : ((i == 1) ? bs1 : bs2);
                        float m = bsv * (invcy * invcx[i]);
                        Aa[i] += m; Bb[i] = fmaf(xv, m, Bb[i]); Cc[i] = fmaf(m, m, Cc[i]);
                    }
                    int e0 = by + 4;  if (e0 >= RING) e0 -= RING;
                    int e1 = by + 8;  if (e1 >= RING) e1 -= RING;
                    int e2 = by + 16; if (e2 >= RING) e2 -= RING;
                    int l0 = by - 3;  if (l0 < 0) l0 += RING;
                    int l1 = by - 7;  if (l1 < 0) l1 += RING;
                    int l2 = by - 15; if (l2 < 0) l2 += RING;
                    const float* pe0 = &ring[e0][t]; const float* pl0 = &ring[l0][t];
                    const float* pe1 = &ring[e1][t]; const float* pl1 = &ring[l1][t];
                    const float* pe2 = &ring[e2][t]; const float* pl2 = &ring[l2][t];
                    bs0 += (pe0[19] - pe0[12]) - (pl0[19] - pl0[12]);
                    bs1 += (pe1[23] - pe1[8])  - (pl1[23] - pl1[8]);
                    bs2 += (pe2[31] - pe2[0])  - (pl2[31] - pl2[0]);
                    ++by; if (by >= RING) by = 0;
                }
            }
        }
    }

    // deterministic block reduction of the 11 accumulators
    float acc[NACC] = {Aa[0], Bb[0], Cc[0], Aa[1], Bb[1], Cc[1],
                       Aa[2], Bb[2], Cc[2], T1, T2};
#pragma unroll
    for (int q = 0; q < NACC; ++q) {
#pragma unroll
        for (int d = 32; d >= 1; d >>= 1) acc[q] += __shfl_xor(acc[q], d, 64);
    }
    if (lane == 0) {
#pragma unroll
        for (int q = 0; q < NACC; ++q) redbuf[wv * NACC + q] = acc[q];
    }
    __syncthreads();
    if (t < NACC) {
        float ssum = 0.f;
#pragma unroll
        for (int w = 0; w < 6; ++w) ssum += redbuf[w * NACC + t];
        partials[bid * NACC + t] = ssum;
    }
}

// ---- per-(plane, l) std -> reciprocal scale; scales[op], op=(b*4+l)*64+c ----
__global__ __launch_bounds__(128) void scales_kernel(const float* __restrict__ partials,
                                                     const float* __restrict__ tiny,
                                                     float* __restrict__ scales) {
    int p = threadIdx.x;
    if (p >= NPLANES) return;
    int b = p >> 6, c = p & 63;
    float acc[NACC];
#pragma unroll
    for (int q = 0; q < NACC; ++q) acc[q] = 0.f;
    for (int s = 0; s < VSTRIPS; ++s) {
#pragma unroll
        for (int q = 0; q < NACC; ++q)
            acc[q] += partials[(p * VSTRIPS + s) * NACC + q];
    }
    const float Nf = (float)HWSZ;
    const float invNm1 = 1.0f / (float)(HWSZ - 1);
    float T1 = acc[9], T2 = acc[10];
    float thr = tiny[c] + 1e-6f;
#pragma unroll
    for (int l = 0; l < 4; ++l) {
        float S, Q;
        if (l < 3) {
            S = T1 - acc[l * 3 + 0];
            Q = T2 - 2.f * acc[l * 3 + 1] + acc[l * 3 + 2];
        } else {
            S = T1;     // var(x - mean(x)) == var(x)
            Q = T2;
        }
        float var = (Q - S * S / Nf) * invNm1;
        float sd = sqrtf(fmaxf(var, 0.f));
        sd = fmaxf(sd, thr);
        scales[(b * 4 + l) * CHN + c] = 1.0f / sd;
    }
}

// ---- out: persistent grid-stride, 1 coalesced read -> 4 nt-store streams (R8 best) ----
__global__ __launch_bounds__(256) void out_kernel(const float* __restrict__ x,
                                                  const float* __restrict__ scales,
                                                  float* __restrict__ out) {
    __shared__ float ls[512];
    ls[threadIdx.x] = scales[threadIdx.x];
    ls[threadIdx.x + 256] = scales[threadIdx.x + 256];
    __syncthreads();

    const unsigned stride = OB * OT;                 // 524288
    const unsigned base = blockIdx.x * OT + threadIdx.x;
    const f4* __restrict__ xq = (const f4*)x;
    f4* __restrict__ oq = (f4*)out;

    f4 v = xq[base];
#pragma unroll
    for (int it = 0; it < OITER; ++it) {
        unsigned i = base + it * stride;
        f4 cur = v;
        if (it + 1 < OITER) v = xq[i + stride];      // prefetch next iter
        unsigned plane = i / QP;                     // wave-uniform (QP%64==0)
        unsigned q = i - plane * QP;
        unsigned b = plane >> 6, c = plane & 63;
        size_t o0 = (size_t)(b * 256 + c) * QP + q;  // l=0 output quad index
#pragma unroll
        for (int l = 0; l < 4; ++l) {
            f4 o = cur * ls[b * 256 + l * 64 + c];
            __builtin_nontemporal_store(o, oq + o0 + (size_t)l * 64 * QP);
        }
    }
}

extern "C" void kernel_launch(void* const* d_in, const int* in_sizes, int n_in,
                              void* d_out, int out_size, void* d_ws, size_t ws_size,
                              hipStream_t stream) {
    const float* x = (const float*)d_in[0];
    const float* tiny = (const float*)d_in[1];
    float* out = (float*)d_out;

    float* partials = (float*)d_ws;                              // 512*11 floats
    float* scales = partials + NPLANES * VSTRIPS * NACC;         // 512 floats

    stats_fused<<<NPLANES * VSTRIPS, 384, 0, stream>>>(x, partials);
    scales_kernel<<<1, 128, 0, stream>>>(partials, tiny, scales);
    out_kernel<<<OB, OT, 0, stream>>>(x, scales, out);
}

// Round 12
// 143.743 us; speedup vs baseline: 2.9176x; 1.0201x over previous
//
#include <hip/hip_runtime.h>

#define HH 384
#define WW 384
#define HWSZ (HH * WW)          // 147456
#define NPLANES 128             // 2 batch * 64 chan
#define CHN 64
#define VSTRIPS 4
#define STRIP_H 96              // HH / VSTRIPS
#define RING 48                 // LDS ring rows
#define RSTRIDE 416             // 16 left pad + 384 + 15 right pad (+1 align)
#define NACC 11
#define NSUP 11                 // 11 stage groups of 12 rows; compute lags 3 groups
#define QP (HWSZ / 4)           // 36864 float4 per plane
#define NINQ (NPLANES * QP)     // 4,718,592 input quads
#define OB 2048
#define OT 256
#define OITER (NINQ / (OB * OT))   // 9, exact

typedef float f4 __attribute__((ext_vector_type(4)));

// 12-row compute group with COMPILE-TIME ring slots (BY0 = phase).
// After unroll, every LDS address is base(t) + literal -> ds_read2 fusion,
// no per-row address chain, free static scheduling.
template<int BY0, bool FAST>
__device__ __forceinline__ void group12(const float (*ring)[RSTRIDE], int t, int Y,
        float& bs0, float& bs1, float& bs2, float& T1, float& T2,
        float Aa[3], float Bb[3], float Cc[3],
        const float fmul[3], const float invcx[3]) {
#pragma unroll
    for (int dy = 0; dy < 12; ++dy) {
        const int sl = (BY0 + dy) % RING;
        const float* pr = &ring[sl][t];
        float xv = pr[16] - pr[15];          // recover x[y][t]
        T1 += xv;
        T2 = fmaf(xv, xv, T2);
        if (FAST) {
            float m0 = bs0 * fmul[0], m1 = bs1 * fmul[1], m2 = bs2 * fmul[2];
            Aa[0] += m0; Bb[0] = fmaf(xv, m0, Bb[0]); Cc[0] = fmaf(m0, m0, Cc[0]);
            Aa[1] += m1; Bb[1] = fmaf(xv, m1, Bb[1]); Cc[1] = fmaf(m1, m1, Cc[1]);
            Aa[2] += m2; Bb[2] = fmaf(xv, m2, Bb[2]); Cc[2] = fmaf(m2, m2, Cc[2]);
        } else {
            const int y = Y + dy;
            const int W2S[3] = {3, 7, 15};
#pragma unroll
            for (int i = 0; i < 3; ++i) {
                int w2 = W2S[i];
                int chi = y + w2; if (chi > HH - 1) chi = HH - 1;
                int clo = y - w2; if (clo < 0) clo = 0;
                float invcy = __builtin_amdgcn_rcpf((float)(chi - clo + 1));
                float bsv = (i == 0) ? bs0 : ((i == 1) ? bs1 : bs2);
                float m = bsv * (invcy * invcx[i]);
                Aa[i] += m; Bb[i] = fmaf(xv, m, Bb[i]); Cc[i] = fmaf(m, m, Cc[i]);
            }
        }
        // advance bsums to y+1: enter y+1+w2 (slots sl+4/8/16), leave y-w2 (sl-3/7/15)
        const int e0 = (sl + 4) % RING, e1 = (sl + 8) % RING, e2 = (sl + 16) % RING;
        const int l0 = (sl + RING - 3) % RING, l1 = (sl + RING - 7) % RING,
                  l2 = (sl + RING - 15) % RING;
        const float* pe0 = &ring[e0][t]; const float* pl0 = &ring[l0][t];
        const float* pe1 = &ring[e1][t]; const float* pl1 = &ring[l1][t];
        const float* pe2 = &ring[e2][t]; const float* pl2 = &ring[l2][t];
        bs0 += (pe0[19] - pe0[12]) - (pl0[19] - pl0[12]);
        bs1 += (pe1[23] - pe1[8])  - (pl1[23] - pl1[8]);
        bs2 += (pe2[31] - pe2[0])  - (pl2[31] - pl2[0]);
    }
}

// Ring row layout: [0..15]=0 (P[-k]), [16+c]=P[c], [400..414]=P[383].
__global__ __launch_bounds__(384, 3) void stats_fused(const float* __restrict__ x,
                                                      float* __restrict__ partials) {
    __shared__ float ring[RING][RSTRIDE];   // 79,872 B
    __shared__ float redbuf[6 * NACC];

    const int t = threadIdx.x;              // column 0..383
    const int lane = t & 63;
    const int wv = t >> 6;
    const int bid = blockIdx.x;
    const int p = bid >> 2;                 // plane
    const int s = bid & 3;                  // strip
    const int y0 = s * STRIP_H;
    const float* __restrict__ xp = x + (size_t)p * HWSZ;

    const int W2S[3] = {3, 7, 15};          // l=0 -> w7, l=1 -> w15, l=2 -> w31
    float invcx[3], fmul[3];
#pragma unroll
    for (int i = 0; i < 3; ++i) {
        int w2 = W2S[i];
        int hi = t + w2; if (hi > WW - 1) hi = WW - 1;
        int lo = t - w2; if (lo < 0) lo = 0;
        invcx[i] = 1.0f / (float)(hi - lo + 1);
        fmul[i] = invcx[i] * (1.0f / (float)(2 * w2 + 1));   // interior invcy folded
    }

    // zero the left pads once (staging never touches cols < 16)
    for (int idx = t; idx < RING * 16; idx += 384)
        ring[idx >> 4][idx & 15] = 0.f;

    float bs0 = 0.f, bs1 = 0.f, bs2 = 0.f;
    float Aa[3] = {0.f, 0.f, 0.f};
    float Bb[3] = {0.f, 0.f, 0.f};
    float Cc[3] = {0.f, 0.f, 0.f};
    float T1 = 0.f, T2 = 0.f;

    // prefetch stage-group 0: wave handles rows u=wv and u=wv+6
    float2 A0 = {0,0}, A1 = {0,0}, A2 = {0,0};
    float2 B0 = {0,0}, B1 = {0,0}, B2 = {0,0};
    {
        int r1 = y0 - 16 + wv;
        if ((unsigned)r1 < (unsigned)HH) {
            const float* src = xp + (size_t)r1 * WW + lane * 6;
            A0 = *(const float2*)(src); A1 = *(const float2*)(src + 2); A2 = *(const float2*)(src + 4);
        }
        int r2 = r1 + 6;
        if ((unsigned)r2 < (unsigned)HH) {
            const float* src = xp + (size_t)r2 * WW + lane * 6;
            B0 = *(const float2*)(src); B1 = *(const float2*)(src + 2); B2 = *(const float2*)(src + 4);
        }
    }

    for (int k = 0; k < NSUP; ++k) {
        const int u1 = 12 * k + wv;         // this wave's two staged rows
        const int u2 = u1 + 6;
        {
            float a0 = A0.x, a1 = a0 + A0.y, a2 = a1 + A1.x;
            float a3 = a2 + A1.y, a4 = a3 + A2.x, a5 = a4 + A2.y;
            float b0 = B0.x, b1 = b0 + B0.y, b2 = b1 + B1.x;
            float b3 = b2 + B1.y, b4 = b3 + B2.x, b5 = b4 + B2.y;
            float ea = a5, eb = b5;
#pragma unroll
            for (int d = 1; d < 64; d <<= 1) {
                float ua = __shfl_up(ea, d, 64);
                float ub = __shfl_up(eb, d, 64);
                if (lane >= d) { ea += ua; eb += ub; }
            }
            ea -= a5; eb -= b5;             // exclusive offsets
            float pa383 = __shfl(a5 + ea, 63, 64);
            float pb383 = __shfl(b5 + eb, 63, 64);
            if (u1 <= 126) {
                int sl = u1; if (sl >= 96) sl -= 96; else if (sl >= 48) sl -= 48;
                float* dst = ring[sl]; float* dp = dst + 16 + lane * 6;
                *(float2*)(dp)     = make_float2(a0 + ea, a1 + ea);
                *(float2*)(dp + 2) = make_float2(a2 + ea, a3 + ea);
                *(float2*)(dp + 4) = make_float2(a4 + ea, a5 + ea);
                if (lane < 15) dst[400 + lane] = pa383;
            }
            if (u2 <= 126) {
                int sl = u2; if (sl >= 96) sl -= 96; else if (sl >= 48) sl -= 48;
                float* dst = ring[sl]; float* dp = dst + 16 + lane * 6;
                *(float2*)(dp)     = make_float2(b0 + eb, b1 + eb);
                *(float2*)(dp + 2) = make_float2(b2 + eb, b3 + eb);
                *(float2*)(dp + 4) = make_float2(b4 + eb, b5 + eb);
                if (lane < 15) dst[400 + lane] = pb383;
            }
        }
        if (k < NSUP - 1) {                 // prefetch next stage group
            A0 = A1 = A2 = B0 = B1 = B2 = make_float2(0.f, 0.f);
            int r1 = y0 - 16 + u1 + 12;
            if (u1 + 12 <= 126 && (unsigned)r1 < (unsigned)HH) {
                const float* src = xp + (size_t)r1 * WW + lane * 6;
                A0 = *(const float2*)(src); A1 = *(const float2*)(src + 2); A2 = *(const float2*)(src + 4);
            }
            int r2 = r1 + 6;
            if (u2 + 12 <= 126 && (unsigned)r2 < (unsigned)HH) {
                const float* src = xp + (size_t)r2 * WW + lane * 6;
                B0 = *(const float2*)(src); B1 = *(const float2*)(src + 2); B2 = *(const float2*)(src + 4);
            }
        }
        __syncthreads();                    // one barrier per superstep (11 total)

        int j = k - 3;
        if (j >= 0) {
            const int Y = y0 + 12 * j;
            if (j == 0) {                   // prime box sums at y = y0 (slots 1..31)
#pragma unroll
                for (int i = 0; i < 3; ++i) {
                    int w2 = W2S[i];
                    float sum = 0.f;
                    for (int rr = -w2; rr <= w2; ++rr) {
                        const float* pr = &ring[16 + rr][t];
                        sum += pr[16 + w2] - pr[15 - w2];
                    }
                    if (i == 0) bs0 = sum; else if (i == 1) bs1 = sum; else bs2 = sum;
                }
            }
            const bool fast = (Y >= 15) && (Y + 11 <= 368);   // wave-uniform
            switch (j & 3) {                // by0 = (16+12j)%48: 16,28,40,4 cycle
            case 0:
                if (fast) group12<16, true >(ring, t, Y, bs0, bs1, bs2, T1, T2, Aa, Bb, Cc, fmul, invcx);
                else      group12<16, false>(ring, t, Y, bs0, bs1, bs2, T1, T2, Aa, Bb, Cc, fmul, invcx);
                break;
            case 1:
                if (fast) group12<28, true >(ring, t, Y, bs0, bs1, bs2, T1, T2, Aa, Bb, Cc, fmul, invcx);
                else      group12<28, false>(ring, t, Y, bs0, bs1, bs2, T1, T2, Aa, Bb, Cc, fmul, invcx);
                break;
            case 2:
                if (fast) group12<40, true >(ring, t, Y, bs0, bs1, bs2, T1, T2, Aa, Bb, Cc, fmul, invcx);
                else      group12<40, false>(ring, t, Y, bs0, bs1, bs2, T1, T2, Aa, Bb, Cc, fmul, invcx);
                break;
            default:
                if (fast) group12<4, true >(ring, t, Y, bs0, bs1, bs2, T1, T2, Aa, Bb, Cc, fmul, invcx);
                else      group12<4, false>(ring, t, Y, bs0, bs1, bs2, T1, T2, Aa, Bb, Cc, fmul, invcx);
                break;
            }
        }
    }

    // deterministic block reduction of the 11 accumulators
    float acc[NACC] = {Aa[0], Bb[0], Cc[0], Aa[1], Bb[1], Cc[1],
                       Aa[2], Bb[2], Cc[2], T1, T2};
#pragma unroll
    for (int q = 0; q < NACC; ++q) {
#pragma unroll
        for (int d = 32; d >= 1; d >>= 1) acc[q] += __shfl_xor(acc[q], d, 64);
    }
    if (lane == 0) {
#pragma unroll
        for (int q = 0; q < NACC; ++q) redbuf[wv * NACC + q] = acc[q];
    }
    __syncthreads();
    if (t < NACC) {
        float ssum = 0.f;
#pragma unroll
        for (int w = 0; w < 6; ++w) ssum += redbuf[w * NACC + t];
        partials[bid * NACC + t] = ssum;
    }
}

// ---- per-(plane, l) std -> reciprocal scale; scales[op], op=(b*4+l)*64+c ----
__global__ __launch_bounds__(128) void scales_kernel(const float* __restrict__ partials,
                                                     const float* __restrict__ tiny,
                                                     float* __restrict__ scales) {
    int p = threadIdx.x;
    if (p >= NPLANES) return;
    int b = p >> 6, c = p & 63;
    float acc[NACC];
#pragma unroll
    for (int q = 0; q < NACC; ++q) acc[q] = 0.f;
    for (int s = 0; s < VSTRIPS; ++s) {
#pragma unroll
        for (int q = 0; q < NACC; ++q)
            acc[q] += partials[(p * VSTRIPS + s) * NACC + q];
    }
    const float Nf = (float)HWSZ;
    const float invNm1 = 1.0f / (float)(HWSZ - 1);
    float T1 = acc[9], T2 = acc[10];
    float thr = tiny[c] + 1e-6f;
#pragma unroll
    for (int l = 0; l < 4; ++l) {
        float S, Q;
        if (l < 3) {
            S = T1 - acc[l * 3 + 0];
            Q = T2 - 2.f * acc[l * 3 + 1] + acc[l * 3 + 2];
        } else {
            S = T1;     // var(x - mean(x)) == var(x)
            Q = T2;
        }
        float var = (Q - S * S / Nf) * invNm1;
        float sd = sqrtf(fmaxf(var, 0.f));
        sd = fmaxf(sd, thr);
        scales[(b * 4 + l) * CHN + c] = 1.0f / sd;
    }
}

// ---- out: persistent grid-stride, 1 coalesced read -> 4 nt-store streams (R8 best) ----
__global__ __launch_bounds__(256) void out_kernel(const float* __restrict__ x,
                                                  const float* __restrict__ scales,
                                                  float* __restrict__ out) {
    __shared__ float ls[512];
    ls[threadIdx.x] = scales[threadIdx.x];
    ls[threadIdx.x + 256] = scales[threadIdx.x + 256];
    __syncthreads();

    const unsigned stride = OB * OT;                 // 524288
    const unsigned base = blockIdx.x * OT + threadIdx.x;
    const f4* __restrict__ xq = (const f4*)x;
    f4* __restrict__ oq = (f4*)out;

    f4 v = xq[base];
#pragma unroll
    for (int it = 0; it < OITER; ++it) {
        unsigned i = base + it * stride;
        f4 cur = v;
        if (it + 1 < OITER) v = xq[i + stride];      // prefetch next iter
        unsigned plane = i / QP;                     // wave-uniform (QP%64==0)
        unsigned q = i - plane * QP;
        unsigned b = plane >> 6, c = plane & 63;
        size_t o0 = (size_t)(b * 256 + c) * QP + q;  // l=0 output quad index
#pragma unroll
        for (int l = 0; l < 4; ++l) {
            f4 o = cur * ls[b * 256 + l * 64 + c];
            __builtin_nontemporal_store(o, oq + o0 + (size_t)l * 64 * QP);
        }
    }
}

extern "C" void kernel_launch(void* const* d_in, const int* in_sizes, int n_in,
                              void* d_out, int out_size, void* d_ws, size_t ws_size,
                              hipStream_t stream) {
    const float* x = (const float*)d_in[0];
    const float* tiny = (const float*)d_in[1];
    float* out = (float*)d_out;

    float* partials = (float*)d_ws;                              // 512*11 floats
    float* scales = partials + NPLANES * VSTRIPS * NACC;         // 512 floats

    stats_fused<<<NPLANES * VSTRIPS, 384, 0, stream>>>(x, partials);
    scales_kernel<<<1, 128, 0, stream>>>(partials, tiny, scales);
    out_kernel<<<OB, OT, 0, stream>>>(x, scales, out);
}

// Round 13
// 133.651 us; speedup vs baseline: 3.1379x; 1.0755x over previous
//
#include <hip/hip_runtime.h>

#define HH 384
#define WW 384
#define HWSZ (HH * WW)          // 147456
#define NPLANES 128             // 2 batch * 64 chan
#define CHN 64
#define VSTRIPS 4
#define STRIP_H 96              // HH / VSTRIPS
#define RING 42                 // minimal ring for G=6, lag=6 (span analysis)
#define RSTRIDE 416             // 16 left pad + 384 + 15 right pad (+1 align)
#define NACC 11
#define NSUP 22                 // 22 stage steps of 6 rows; compute lags 6
#define QP (HWSZ / 4)           // 36864 float4 per plane
#define NINQ (NPLANES * QP)     // 4,718,592 input quads
#define OB 2048
#define OT 256
#define OITER (NINQ / (OB * OT))   // 9, exact

typedef float f4 __attribute__((ext_vector_type(4)));

// 6-row compute group, COMPILE-TIME ring slots (BY0 = phase of (6j+16)%42).
template<int BY0, bool FAST>
__device__ __forceinline__ void group6(const float (*ring)[RSTRIDE], int t, int Y,
        float& bs0, float& bs1, float& bs2, float& T1, float& T2,
        float Aa[3], float Bb[3], float Cc[3],
        const float fmul[3], const float invcx[3]) {
#pragma unroll
    for (int dy = 0; dy < 6; ++dy) {
        const int sl = (BY0 + dy) % RING;
        const float* pr = &ring[sl][t];
        float xv = pr[16] - pr[15];          // recover x[y][t]
        T1 += xv;
        T2 = fmaf(xv, xv, T2);
        if (FAST) {
            float m0 = bs0 * fmul[0], m1 = bs1 * fmul[1], m2 = bs2 * fmul[2];
            Aa[0] += m0; Bb[0] = fmaf(xv, m0, Bb[0]); Cc[0] = fmaf(m0, m0, Cc[0]);
            Aa[1] += m1; Bb[1] = fmaf(xv, m1, Bb[1]); Cc[1] = fmaf(m1, m1, Cc[1]);
            Aa[2] += m2; Bb[2] = fmaf(xv, m2, Bb[2]); Cc[2] = fmaf(m2, m2, Cc[2]);
        } else {
            const int y = Y + dy;
            const int W2S[3] = {3, 7, 15};
#pragma unroll
            for (int i = 0; i < 3; ++i) {
                int w2 = W2S[i];
                int chi = y + w2; if (chi > HH - 1) chi = HH - 1;
                int clo = y - w2; if (clo < 0) clo = 0;
                float invcy = __builtin_amdgcn_rcpf((float)(chi - clo + 1));
                float bsv = (i == 0) ? bs0 : ((i == 1) ? bs1 : bs2);
                float m = bsv * (invcy * invcx[i]);
                Aa[i] += m; Bb[i] = fmaf(xv, m, Bb[i]); Cc[i] = fmaf(m, m, Cc[i]);
            }
        }
        // advance to y+1: enter slots sl+{4,8,16}, leave slots sl-{3,7,15}
        const int e0 = (sl + 4) % RING, e1 = (sl + 8) % RING, e2 = (sl + 16) % RING;
        const int l0 = (sl + RING - 3) % RING, l1 = (sl + RING - 7) % RING,
                  l2 = (sl + RING - 15) % RING;
        const float* pe0 = &ring[e0][t]; const float* pl0 = &ring[l0][t];
        const float* pe1 = &ring[e1][t]; const float* pl1 = &ring[l1][t];
        const float* pe2 = &ring[e2][t]; const float* pl2 = &ring[l2][t];
        bs0 += (pe0[19] - pe0[12]) - (pl0[19] - pl0[12]);
        bs1 += (pe1[23] - pe1[8])  - (pl1[23] - pl1[8]);
        bs2 += (pe2[31] - pe2[0])  - (pl2[31] - pl2[0]);
    }
}

// Ring row layout: [0..15]=0 (P[-k]), [16+c]=P[c], [400..414]=P[383].
__global__ __launch_bounds__(384, 3) void stats_fused(const float* __restrict__ x,
                                                      float* __restrict__ partials) {
    __shared__ float ring[RING][RSTRIDE];   // 69,888 B -> 2 blocks/CU
    __shared__ float redbuf[6 * NACC];

    const int t = threadIdx.x;              // column 0..383
    const int lane = t & 63;
    const int wv = t >> 6;
    const int bid = blockIdx.x;
    const int p = bid >> 2;                 // plane
    const int s = bid & 3;                  // strip
    const int y0 = s * STRIP_H;
    const float* __restrict__ xp = x + (size_t)p * HWSZ;

    const int W2S[3] = {3, 7, 15};          // l=0 -> w7, l=1 -> w15, l=2 -> w31
    float invcx[3], fmul[3];
#pragma unroll
    for (int i = 0; i < 3; ++i) {
        int w2 = W2S[i];
        int hi = t + w2; if (hi > WW - 1) hi = WW - 1;
        int lo = t - w2; if (lo < 0) lo = 0;
        invcx[i] = 1.0f / (float)(hi - lo + 1);
        fmul[i] = invcx[i] * (1.0f / (float)(2 * w2 + 1));   // interior invcy folded
    }

    // zero the left pads once (staging never touches cols < 16)
    for (int idx = t; idx < RING * 16; idx += 384)
        ring[idx >> 4][idx & 15] = 0.f;

    float bs0 = 0.f, bs1 = 0.f, bs2 = 0.f;
    float Aa[3] = {0.f, 0.f, 0.f};
    float Bb[3] = {0.f, 0.f, 0.f};
    float Cc[3] = {0.f, 0.f, 0.f};
    float T1 = 0.f, T2 = 0.f;

    // prefetch stage-step 0: wave wv handles row u = wv
    float2 A0 = {0,0}, A1 = {0,0}, A2 = {0,0};
    {
        int r = y0 - 16 + wv;
        if ((unsigned)r < (unsigned)HH) {
            const float* src = xp + (size_t)r * WW + lane * 6;
            A0 = *(const float2*)(src); A1 = *(const float2*)(src + 2); A2 = *(const float2*)(src + 4);
        }
    }

    for (int k = 0; k < NSUP; ++k) {
        const int u = 6 * k + wv;           // this wave's staged row index
        const int r = y0 - 16 + u;
        if (u <= 126) {
            int sl = u; if (sl >= 84) sl -= 84; if (sl >= 42) sl -= 42;
            float* dst = ring[sl];
            if ((unsigned)r < (unsigned)HH) {
                float s0 = A0.x, s1 = s0 + A0.y, s2 = s1 + A1.x;
                float s3 = s2 + A1.y, s4 = s3 + A2.x, s5 = s4 + A2.y;
                float tot = s5, e = tot;
#pragma unroll
                for (int d = 1; d < 64; d <<= 1) {
                    float uu = __shfl_up(e, d, 64);
                    if (lane >= d) e += uu;
                }
                e -= tot;                   // exclusive offset of lane totals
                float p383 = __shfl(s5 + e, 63, 64);
                float* dp = dst + 16 + lane * 6;
                *(float2*)(dp)     = make_float2(s0 + e, s1 + e);
                *(float2*)(dp + 2) = make_float2(s2 + e, s3 + e);
                *(float2*)(dp + 4) = make_float2(s4 + e, s5 + e);
                if (lane < 15) dst[400 + lane] = p383;   // right pad = P[383]
            } else {
                float* dp = dst + 16 + lane * 6;
                *(float2*)(dp)     = make_float2(0.f, 0.f);
                *(float2*)(dp + 2) = make_float2(0.f, 0.f);
                *(float2*)(dp + 4) = make_float2(0.f, 0.f);
                if (lane < 15) dst[400 + lane] = 0.f;
            }
        }
        if (k < NSUP - 1) {                 // prefetch next step's row
            A0 = A1 = A2 = make_float2(0.f, 0.f);
            int rn = r + 6;
            if (u + 6 <= 126 && (unsigned)rn < (unsigned)HH) {
                const float* src = xp + (size_t)rn * WW + lane * 6;
                A0 = *(const float2*)(src); A1 = *(const float2*)(src + 2); A2 = *(const float2*)(src + 4);
            }
        }
        __syncthreads();                    // one barrier per superstep (22 total)

        int j = k - 6;
        if (j >= 0) {
            const int Y = y0 + 6 * j;
            if (j == 0) {                   // prime box sums at y = y0 (slots 1..31)
#pragma unroll
                for (int i = 0; i < 3; ++i) {
                    int w2 = W2S[i];
                    float sum = 0.f;
                    for (int rr = -w2; rr <= w2; ++rr) {
                        const float* pr = &ring[16 + rr][t];
                        sum += pr[16 + w2] - pr[15 - w2];
                    }
                    if (i == 0) bs0 = sum; else if (i == 1) bs1 = sum; else bs2 = sum;
                }
            }
            const bool fast = (Y >= 15) && (Y <= 363);     // wave-uniform
            switch (j % 7) {                // by0 = (16+6j)%42: {16,22,28,34,40,4,10}
            case 0:
                if (fast) group6<16, true >(ring, t, Y, bs0, bs1, bs2, T1, T2, Aa, Bb, Cc, fmul, invcx);
                else      group6<16, false>(ring, t, Y, bs0, bs1, bs2, T1, T2, Aa, Bb, Cc, fmul, invcx);
                break;
            case 1:
                if (fast) group6<22, true >(ring, t, Y, bs0, bs1, bs2, T1, T2, Aa, Bb, Cc, fmul, invcx);
                else      group6<22, false>(ring, t, Y, bs0, bs1, bs2, T1, T2, Aa, Bb, Cc, fmul, invcx);
                break;
            case 2:
                if (fast) group6<28, true >(ring, t, Y, bs0, bs1, bs2, T1, T2, Aa, Bb, Cc, fmul, invcx);
                else      group6<28, false>(ring, t, Y, bs0, bs1, bs2, T1, T2, Aa, Bb, Cc, fmul, invcx);
                break;
            case 3:
                if (fast) group6<34, true >(ring, t, Y, bs0, bs1, bs2, T1, T2, Aa, Bb, Cc, fmul, invcx);
                else      group6<34, false>(ring, t, Y, bs0, bs1, bs2, T1, T2, Aa, Bb, Cc, fmul, invcx);
                break;
            case 4:
                if (fast) group6<40, true >(ring, t, Y, bs0, bs1, bs2, T1, T2, Aa, Bb, Cc, fmul, invcx);
                else      group6<40, false>(ring, t, Y, bs0, bs1, bs2, T1, T2, Aa, Bb, Cc, fmul, invcx);
                break;
            case 5:
                if (fast) group6<4, true >(ring, t, Y, bs0, bs1, bs2, T1, T2, Aa, Bb, Cc, fmul, invcx);
                else      group6<4, false>(ring, t, Y, bs0, bs1, bs2, T1, T2, Aa, Bb, Cc, fmul, invcx);
                break;
            default:
                if (fast) group6<10, true >(ring, t, Y, bs0, bs1, bs2, T1, T2, Aa, Bb, Cc, fmul, invcx);
                else      group6<10, false>(ring, t, Y, bs0, bs1, bs2, T1, T2, Aa, Bb, Cc, fmul, invcx);
                break;
            }
        }
    }

    // deterministic block reduction of the 11 accumulators
    float acc[NACC] = {Aa[0], Bb[0], Cc[0], Aa[1], Bb[1], Cc[1],
                       Aa[2], Bb[2], Cc[2], T1, T2};
#pragma unroll
    for (int q = 0; q < NACC; ++q) {
#pragma unroll
        for (int d = 32; d >= 1; d >>= 1) acc[q] += __shfl_xor(acc[q], d, 64);
    }
    if (lane == 0) {
#pragma unroll
        for (int q = 0; q < NACC; ++q) redbuf[wv * NACC + q] = acc[q];
    }
    __syncthreads();
    if (t < NACC) {
        float ssum = 0.f;
#pragma unroll
        for (int w = 0; w < 6; ++w) ssum += redbuf[w * NACC + t];
        partials[bid * NACC + t] = ssum;
    }
}

// ---- per-(plane, l) std -> reciprocal scale; scales[op], op=(b*4+l)*64+c ----
__global__ __launch_bounds__(128) void scales_kernel(const float* __restrict__ partials,
                                                     const float* __restrict__ tiny,
                                                     float* __restrict__ scales) {
    int p = threadIdx.x;
    if (p >= NPLANES) return;
    int b = p >> 6, c = p & 63;
    float acc[NACC];
#pragma unroll
    for (int q = 0; q < NACC; ++q) acc[q] = 0.f;
    for (int s = 0; s < VSTRIPS; ++s) {
#pragma unroll
        for (int q = 0; q < NACC; ++q)
            acc[q] += partials[(p * VSTRIPS + s) * NACC + q];
    }
    const float Nf = (float)HWSZ;
    const float invNm1 = 1.0f / (float)(HWSZ - 1);
    float T1 = acc[9], T2 = acc[10];
    float thr = tiny[c] + 1e-6f;
#pragma unroll
    for (int l = 0; l < 4; ++l) {
        float S, Q;
        if (l < 3) {
            S = T1 - acc[l * 3 + 0];
            Q = T2 - 2.f * acc[l * 3 + 1] + acc[l * 3 + 2];
        } else {
            S = T1;     // var(x - mean(x)) == var(x)
            Q = T2;
        }
        float var = (Q - S * S / Nf) * invNm1;
        float sd = sqrtf(fmaxf(var, 0.f));
        sd = fmaxf(sd, thr);
        scales[(b * 4 + l) * CHN + c] = 1.0f / sd;
    }
}

// ---- out: persistent grid-stride, 1 coalesced read -> 4 nt-store streams (R8 best) ----
__global__ __launch_bounds__(256) void out_kernel(const float* __restrict__ x,
                                                  const float* __restrict__ scales,
                                                  float* __restrict__ out) {
    __shared__ float ls[512];
    ls[threadIdx.x] = scales[threadIdx.x];
    ls[threadIdx.x + 256] = scales[threadIdx.x + 256];
    __syncthreads();

    const unsigned stride = OB * OT;                 // 524288
    const unsigned base = blockIdx.x * OT + threadIdx.x;
    const f4* __restrict__ xq = (const f4*)x;
    f4* __restrict__ oq = (f4*)out;

    f4 v = xq[base];
#pragma unroll
    for (int it = 0; it < OITER; ++it) {
        unsigned i = base + it * stride;
        f4 cur = v;
        if (it + 1 < OITER) v = xq[i + stride];      // prefetch next iter
        unsigned plane = i / QP;                     // wave-uniform (QP%64==0)
        unsigned q = i - plane * QP;
        unsigned b = plane >> 6, c = plane & 63;
        size_t o0 = (size_t)(b * 256 + c) * QP + q;  // l=0 output quad index
#pragma unroll
        for (int l = 0; l < 4; ++l) {
            f4 o = cur * ls[b * 256 + l * 64 + c];
            __builtin_nontemporal_store(o, oq + o0 + (size_t)l * 64 * QP);
        }
    }
}

extern "C" void kernel_launch(void* const* d_in, const int* in_sizes, int n_in,
                              void* d_out, int out_size, void* d_ws, size_t ws_size,
                              hipStream_t stream) {
    const float* x = (const float*)d_in[0];
    const float* tiny = (const float*)d_in[1];
    float* out = (float*)d_out;

    float* partials = (float*)d_ws;                              // 512*11 floats
    float* scales = partials + NPLANES * VSTRIPS * NACC;         // 512 floats

    stats_fused<<<NPLANES * VSTRIPS, 384, 0, stream>>>(x, partials);
    scales_kernel<<<1, 128, 0, stream>>>(partials, tiny, scales);
    out_kernel<<<OB, OT, 0, stream>>>(x, scales, out);
}